// Round 15
// baseline (725.960 us; speedup 1.0000x reference)
//
#include <hip/hip_runtime.h>
#include <hip/hip_bf16.h>
#include <math.h>

#define N_ATOMS 50000
#define N_EDGES 1600000
#define FDIM 128
#define NB 25
#define CUTOFF_F 5.0f
#define PI_OVER_CUTOFF 0.6283185307179586f
#define NCH 196   // scan chunks of 256
#define NBLK 512  // persistent blocks for edge kernel

typedef __bf16 bf16x8 __attribute__((ext_vector_type(8)));
typedef float f32x4 __attribute__((ext_vector_type(4)));

__device__ __forceinline__ float swish_f(float v) {
    return v / (1.0f + __expf(-v));
}

// XOR swizzle on 16B slots (for 256B-stride hs rows).
#define SWZ(row) ((((row) & 7) ^ (((row) >> 3) & 1)) << 4)

// ---------------- sort-by-dst machinery (r12-proven) ----------------

__global__ void hist_kernel(const int* __restrict__ dst, int* __restrict__ count) {
    int i = blockIdx.x * 256 + threadIdx.x;
    if (i < N_EDGES) atomicAdd(&count[dst[i]], 1);
}

__global__ __launch_bounds__(256) void scan_chunk_kernel(
    const int* __restrict__ count, int* __restrict__ chunksum)
{
    __shared__ int red[256];
    const int t = threadIdx.x;
    const int i = blockIdx.x * 256 + t;
    red[t] = (i < N_ATOMS) ? count[i] : 0;
    __syncthreads();
    for (int o = 128; o > 0; o >>= 1) {
        if (t < o) red[t] += red[t + o];
        __syncthreads();
    }
    if (t == 0) chunksum[blockIdx.x] = red[0];
}

__global__ __launch_bounds__(256) void scan_base_kernel(int* __restrict__ chunksum) {
    __shared__ int sa[256], sb[256];
    const int t = threadIdx.x;
    int v = (t < NCH) ? chunksum[t] : 0;
    sa[t] = v;
    __syncthreads();
    int* cur = sa; int* nxt = sb;
    for (int o = 1; o < 256; o <<= 1) {
        int val = cur[t];
        if (t >= o) val += cur[t - o];
        nxt[t] = val;
        __syncthreads();
        int* tmp = cur; cur = nxt; nxt = tmp;
    }
    if (t < NCH) chunksum[t] = cur[t] - v;   // exclusive
}

__global__ __launch_bounds__(256) void scan_apply_kernel(
    const int* __restrict__ count, const int* __restrict__ chunksum,
    int* __restrict__ cursor)
{
    __shared__ int sa[256], sb[256];
    const int t = threadIdx.x;
    const int i = blockIdx.x * 256 + t;
    int v = (i < N_ATOMS) ? count[i] : 0;
    sa[t] = v;
    __syncthreads();
    int* cur = sa; int* nxt = sb;
    for (int o = 1; o < 256; o <<= 1) {
        int val = cur[t];
        if (t >= o) val += cur[t - o];
        nxt[t] = val;
        __syncthreads();
        int* tmp = cur; cur = nxt; nxt = tmp;
    }
    if (i < N_ATOMS) cursor[i] = chunksum[blockIdx.x] + cur[t] - v;  // exclusive
}

__global__ void scatter_kernel(const int* __restrict__ dst, int* __restrict__ cursor,
                               int* __restrict__ perm) {
    int i = blockIdx.x * 256 + threadIdx.x;
    if (i < N_EDGES) {
        int d = dst[i];
        int p = atomicAdd(&cursor[d], 1);
        perm[p] = i;
    }
}

// ---------------- pre-pass: fij -> bf16 padded rows (streaming) ----------------
// fijb[e*32 + k] = bf16(fij[e*25 + k]) for k<25, else 0. 64 B/row, aligned.

__global__ __launch_bounds__(256) void cvt_fij_kernel(
    const float* __restrict__ fij, __bf16* __restrict__ fijb)
{
    int tid = blockIdx.x * 256 + threadIdx.x;   // one thread per quarter-row
    if (tid >= N_EDGES * 4) return;
    int q = tid & 3;
    int r = tid >> 2;
    const float* fp = fij + (size_t)r * NB;
    bf16x8 o;
    #pragma unroll
    for (int j = 0; j < 8; ++j) {
        int k = (q << 3) + j;
        o[j] = (k < NB) ? (__bf16)fp[k] : (__bf16)0.0f;
    }
    *(bf16x8*)&fijb[((size_t)r << 5) + (q << 3)] = o;
}

// ---------------- pre-pass: sorted headers {src, dst, C, e} ----------------

__global__ __launch_bounds__(256) void hdr_kernel(
    const int* __restrict__ perm, const int* __restrict__ src,
    const int* __restrict__ dst, const float* __restrict__ rij,
    int4* __restrict__ hdr)
{
    int i = blockIdx.x * 256 + threadIdx.x;
    if (i >= N_EDGES) return;
    int e = perm[i];
    float rr = rij[e];
    float C = (rr < CUTOFF_F) ? 0.5f * (__cosf(rr * PI_OVER_CUTOFF) + 1.0f) : 0.0f;
    int4 h;
    h.x = src[e];
    h.y = dst[e];
    h.z = __float_as_int(C);
    h.w = e;
    hdr[i] = h;
}

// ---------------- weight packing ----------------

__global__ void pack_b_kernel(const float* __restrict__ W, __bf16* __restrict__ out,
                              int K_eff, int KS)
{
    int idx = blockIdx.x * 256 + threadIdx.x;
    int total = KS * 8 * 64 * 8;
    if (idx >= total) return;
    int j  = idx & 7;
    int l  = (idx >> 3) & 63;
    int n  = (idx >> 9) & 7;
    int ks = idx >> 12;
    int k   = ks * 32 + ((l >> 4) << 3) + j;
    int col = (n << 4) + (l & 15);
    float v = (k < K_eff) ? W[k * FDIM + col] : 0.0f;
    out[idx] = (__bf16)v;
}

// ---------------- MFMA node GEMM (r12-proven) ----------------

__global__ __launch_bounds__(512, 2) void node_mfma_kernel(
    const float* __restrict__ A, const __bf16* __restrict__ wp,
    const float* __restrict__ bias,
    __bf16* __restrict__ out_bf, float* __restrict__ out_f32,
    int do_swish)
{
    __shared__ __bf16 ws_[16384];   // 32 KB packed B

    const int t = threadIdx.x;
    const int l = t & 63;
    const int w = t >> 6;
    const int lrow = l & 15;
    const int kgrp = l >> 4;

    {
        const int4* g = (const int4*)wp;
        int4* s = (int4*)ws_;
        for (int i = t; i < 2048; i += 512) s[i] = g[i];
    }
    float br[8];
    #pragma unroll
    for (int n = 0; n < 8; ++n) br[n] = bias ? bias[(n << 4) + lrow] : 0.0f;
    __syncthreads();

    const int tile = blockIdx.x * 8 + w;
    if (tile >= N_ATOMS / 16) return;
    const int row0 = tile << 4;

    bf16x8 af[4];
    const float* ap = A + (size_t)(row0 + lrow) * FDIM + (kgrp << 3);
    #pragma unroll
    for (int ks = 0; ks < 4; ++ks) {
        float4 lo = *(const float4*)(ap + (ks << 5));
        float4 hi = *(const float4*)(ap + (ks << 5) + 4);
        af[ks][0] = (__bf16)lo.x; af[ks][1] = (__bf16)lo.y;
        af[ks][2] = (__bf16)lo.z; af[ks][3] = (__bf16)lo.w;
        af[ks][4] = (__bf16)hi.x; af[ks][5] = (__bf16)hi.y;
        af[ks][6] = (__bf16)hi.z; af[ks][7] = (__bf16)hi.w;
    }

    const f32x4 zero = {0.f, 0.f, 0.f, 0.f};
    f32x4 acc[8];
    #pragma unroll
    for (int n = 0; n < 8; ++n) acc[n] = zero;

    #pragma unroll
    for (int ks = 0; ks < 4; ++ks) {
        bf16x8 bfr[8];
        #pragma unroll
        for (int n = 0; n < 8; ++n)
            bfr[n] = *(const bf16x8*)((const char*)ws_ + (((ks << 3) + n) << 10) + (l << 4));
        #pragma unroll
        for (int n = 0; n < 8; ++n)
            acc[n] = __builtin_amdgcn_mfma_f32_16x16x32_bf16(af[ks], bfr[n], acc[n], 0, 0, 0);
    }

    if (out_bf) {
        #pragma unroll
        for (int r = 0; r < 4; ++r) {
            bf16x8 o;
            #pragma unroll
            for (int n = 0; n < 8; ++n) {
                float v = acc[n][r] + br[n];
                if (do_swish) v = swish_f(v);
                o[n] = (__bf16)v;
            }
            *(bf16x8*)&out_bf[(size_t)(row0 + (kgrp << 2) + r) * FDIM + (lrow << 3)] = o;
        }
    } else {
        #pragma unroll
        for (int r = 0; r < 4; ++r) {
            int orow = row0 + (kgrp << 2) + r;
            #pragma unroll
            for (int n = 0; n < 8; ++n) {
                float v = acc[n][r] + br[n];
                if (do_swish) v = swish_f(v);
                out_f32[(size_t)orow * FDIM + (n << 4) + lrow] = v;
            }
        }
    }
}

// ---------------- persistent-wave MFMA edge kernel ----------------
// PRE=true: GATHER = 1 coalesced int4 hdr + 1 aligned b128 fijb (prefetched).
// PRE=false: r14 legacy gather from fij/src/dst/rij via perm (2-deep).
// Back-end (GEMM1/GEMM2/epilogue) identical to r12/r14 best-known.

struct TR {
    bf16x8 a;            // fij A-fragment (bf16)
    int se, de;          // own edge src/dst
    float Cf;            // own edge cutoff factor
};

template<bool PRE>
__global__ __launch_bounds__(512, 2) void edge_kernel(
    const float* __restrict__ fij, const float* __restrict__ rij,
    const int* __restrict__ src, const int* __restrict__ dst,
    const int* __restrict__ perm, const int4* __restrict__ hdr,
    const __bf16* __restrict__ fijb,
    const __bf16* __restrict__ w1p, const float* __restrict__ b1,
    const __bf16* __restrict__ w2p, const float* __restrict__ b2,
    const __bf16* __restrict__ xb, float* __restrict__ agg)
{
    __shared__ __bf16 w2s[16384];       // 32 KB: W2 B-fragments
    __shared__ __bf16 hs[8][16 * 128];  // 32 KB: per-wave H tiles

    const int t = threadIdx.x;
    const int l = t & 63;
    const int w = t >> 6;               // 0..7
    const int lrow = l & 15;
    const int kgrp = l >> 4;

    {
        const int4* g2 = (const int4*)w2p;
        int4* s2 = (int4*)w2s;
        for (int i = t; i < 2048; i += 512) s2[i] = g2[i];
    }

    bf16x8 w1f[8];
    float b1r[8], b2r[8];
    #pragma unroll
    for (int n = 0; n < 8; ++n) {
        w1f[n] = *(const bf16x8*)(w1p + (((n << 6) + l) << 3));
        b1r[n] = b1[(n << 4) + lrow];
        b2r[n] = b2[(n << 4) + lrow];
    }
    __syncthreads();   // w2s ready; last barrier in the kernel

    __bf16* hw = hs[w];
    const f32x4 zero = {0.f, 0.f, 0.f, 0.f};

    const int gw = blockIdx.x * 8 + w;
    const int NW = NBLK * 8;
    const int NT = N_EDGES / 16;
    if (gw >= NT) return;

    TR cur, nxt;
    int4 hN;          // PRE: hdr for next tile
    int pvB = 0;      // legacy: perm for next tile

    if (PRE) {
        int4 h0 = hdr[(gw << 4) + lrow];
        cur.a = *(const bf16x8*)&fijb[((size_t)(unsigned)h0.w << 5) + (kgrp << 3)];
        cur.se = h0.x; cur.de = h0.y; cur.Cf = __int_as_float(h0.z);
        int i2 = gw + NW; i2 = (i2 < NT) ? i2 : (NT - 1);
        hN = hdr[(i2 << 4) + lrow];
    } else {
        int pvA = perm[(gw << 4) + lrow];
        {
            const float* fp = fij + (size_t)pvA * NB;
            float4 f0, f1;
            if (kgrp < 3) {
                f0 = *(const float4*)(fp + (kgrp << 3));
                f1 = *(const float4*)(fp + (kgrp << 3) + 4);
            } else {
                f0 = make_float4(fp[24], 0.f, 0.f, 0.f);
                f1 = make_float4(0.f, 0.f, 0.f, 0.f);
            }
            cur.a[0] = (__bf16)f0.x; cur.a[1] = (__bf16)f0.y;
            cur.a[2] = (__bf16)f0.z; cur.a[3] = (__bf16)f0.w;
            cur.a[4] = (__bf16)f1.x; cur.a[5] = (__bf16)f1.y;
            cur.a[6] = (__bf16)f1.z; cur.a[7] = (__bf16)f1.w;
            cur.se = src[pvA]; cur.de = dst[pvA];
            float rr = rij[pvA];
            cur.Cf = (rr < CUTOFF_F) ? 0.5f * (__cosf(rr * PI_OVER_CUTOFF) + 1.0f) : 0.0f;
        }
        int i2 = gw + NW; i2 = (i2 < NT) ? i2 : (NT - 1);
        pvB = perm[(i2 << 4) + lrow];
    }

    for (int tb = gw; tb < NT; tb += NW) {
        // ---- prefetch next tile (data loaded last iteration breaks the chain) ----
        if (PRE) {
            nxt.a = *(const bf16x8*)&fijb[((size_t)(unsigned)hN.w << 5) + (kgrp << 3)];
            nxt.se = hN.x; nxt.de = hN.y; nxt.Cf = __int_as_float(hN.z);
            int i3 = tb + 2 * NW; i3 = (i3 < NT) ? i3 : (NT - 1);
            hN = hdr[(i3 << 4) + lrow];
        } else {
            {
                const float* fp = fij + (size_t)pvB * NB;
                float4 f0, f1;
                if (kgrp < 3) {
                    f0 = *(const float4*)(fp + (kgrp << 3));
                    f1 = *(const float4*)(fp + (kgrp << 3) + 4);
                } else {
                    f0 = make_float4(fp[24], 0.f, 0.f, 0.f);
                    f1 = make_float4(0.f, 0.f, 0.f, 0.f);
                }
                nxt.a[0] = (__bf16)f0.x; nxt.a[1] = (__bf16)f0.y;
                nxt.a[2] = (__bf16)f0.z; nxt.a[3] = (__bf16)f0.w;
                nxt.a[4] = (__bf16)f1.x; nxt.a[5] = (__bf16)f1.y;
                nxt.a[6] = (__bf16)f1.z; nxt.a[7] = (__bf16)f1.w;
                nxt.se = src[pvB]; nxt.de = dst[pvB];
                float rr = rij[pvB];
                nxt.Cf = (rr < CUTOFF_F) ? 0.5f * (__cosf(rr * PI_OVER_CUTOFF) + 1.0f) : 0.0f;
            }
            int i3 = tb + 2 * NW; i3 = (i3 < NT) ? i3 : (NT - 1);
            pvB = perm[(i3 << 4) + lrow];
        }

        // ---- epilogue prep: shfl headers + issue xv loads early ----
        int se4[4], de4[4]; float Cf[4];
        #pragma unroll
        for (int r = 0; r < 4; ++r) {
            se4[r] = __shfl(cur.se, (kgrp << 2) + r);
            Cf[r]  = __shfl(cur.Cf, (kgrp << 2) + r);
            de4[r] = __shfl(cur.de, (kgrp << 2) + r);
        }
        bf16x8 xv4[4];
        #pragma unroll
        for (int r = 0; r < 4; ++r)
            xv4[r] = *(const bf16x8*)&xb[(size_t)se4[r] * FDIM + (lrow << 3)];

        // ---- GEMM1: H = swish(fij_pad @ W1 + b1) -> hw (wave-local) ----
        #pragma unroll
        for (int n = 0; n < 8; ++n) {
            f32x4 h = __builtin_amdgcn_mfma_f32_16x16x32_bf16(cur.a, w1f[n], zero, 0, 0, 0);
            #pragma unroll
            for (int r = 0; r < 4; ++r) {
                int hrow = (kgrp << 2) + r;
                float hv = swish_f(h[r] + b1r[n]);
                int byte = (hrow << 8) + (((n << 4) + lrow) << 1);
                byte ^= SWZ(hrow);
                *(__bf16*)((char*)hw + byte) = (__bf16)hv;
            }
        }
        // no barrier: hw is wave-local (same-wave DS ops are ordered)

        // ---- GEMM2: Wfilt = H @ W2 (B-frags batched from LDS) ----
        f32x4 acc[8];
        #pragma unroll
        for (int n = 0; n < 8; ++n) acc[n] = zero;

        #pragma unroll
        for (int ks = 0; ks < 4; ++ks) {
            int byte = (lrow << 8) + (ks << 6) + (kgrp << 4);
            byte ^= SWZ(lrow);
            bf16x8 a2 = *(const bf16x8*)((const char*)hw + byte);
            bf16x8 bfr[8];
            #pragma unroll
            for (int n = 0; n < 8; ++n)
                bfr[n] = *(const bf16x8*)((const char*)w2s + (((ks << 3) + n) << 10) + (l << 4));
            #pragma unroll
            for (int n = 0; n < 8; ++n)
                acc[n] = __builtin_amdgcn_mfma_f32_16x16x32_bf16(a2, bfr[n], acc[n], 0, 0, 0);
        }

        // ---- Epilogue: uni fast path + run-compressed atomics (r12-proven) ----
        int d0 = __shfl(cur.de, 0);
        bool uni = __all(cur.de == d0);

        if (uni) {
            const size_t dbase = (size_t)d0 * FDIM;
            #pragma unroll
            for (int n = 0; n < 8; ++n) {
                float s = 0.f;
                #pragma unroll
                for (int r = 0; r < 4; ++r)
                    s += (float)xv4[r][n] * (acc[n][r] + b2r[n]) * Cf[r];
                s += __shfl_xor(s, 16);
                s += __shfl_xor(s, 32);
                if (kgrp == 0) unsafeAtomicAdd(&agg[dbase + (n << 4) + lrow], s);
            }
        } else {
            const bool brk0 = (de4[0] != de4[1]);
            const bool brk1 = (de4[1] != de4[2]);
            const bool brk2 = (de4[2] != de4[3]);
            #pragma unroll
            for (int n = 0; n < 8; ++n) {
                int col = (n << 4) + lrow;
                float m[4];
                #pragma unroll
                for (int r = 0; r < 4; ++r)
                    m[r] = (float)xv4[r][n] * (acc[n][r] + b2r[n]) * Cf[r];
                float run = m[0];
                if (brk0) { unsafeAtomicAdd(&agg[(size_t)de4[0] * FDIM + col], run); run = 0.f; }
                run += m[1];
                if (brk1) { unsafeAtomicAdd(&agg[(size_t)de4[1] * FDIM + col], run); run = 0.f; }
                run += m[2];
                if (brk2) { unsafeAtomicAdd(&agg[(size_t)de4[2] * FDIM + col], run); run = 0.f; }
                run += m[3];
                unsafeAtomicAdd(&agg[(size_t)de4[3] * FDIM + col], run);
            }
        }

        cur = nxt;
    }
}

extern "C" void kernel_launch(void* const* d_in, const int* in_sizes, int n_in,
                              void* d_out, int out_size, void* d_ws, size_t ws_size,
                              hipStream_t stream)
{
    const float* feat   = (const float*)d_in[0];
    const float* fij    = (const float*)d_in[1];
    const float* rij    = (const float*)d_in[2];
    const int*   src    = (const int*)d_in[3];
    const int*   dst    = (const int*)d_in[4];
    const float* W_in2f = (const float*)d_in[5];
    const float* W_f1   = (const float*)d_in[6];
    const float* b_f1   = (const float*)d_in[7];
    const float* W_f2   = (const float*)d_in[8];
    const float* b_f2   = (const float*)d_in[9];
    const float* W_out  = (const float*)d_in[10];
    const float* b_out  = (const float*)d_in[11];
    float* out = (float*)d_out;

    // base ws layout (r14-proven, 19,707,520 B)
    char* ws = (char*)d_ws;
    __bf16* xb       = (__bf16*)ws;                   // 12,800,000 B
    __bf16* w1p      = (__bf16*)(ws + 12800000);      //      8,192 B
    __bf16* w2p      = (__bf16*)(ws + 12808192);      //     32,768 B
    __bf16* winp     = (__bf16*)(ws + 12840960);      //     32,768 B
    __bf16* woutp    = (__bf16*)(ws + 12873728);      //     32,768 B
    int*    cursor   = (int*)(ws + 12906496);         //    200,000 B
    int*    count    = (int*)(ws + 13106496);         //    200,000 B
    int*    chunksum = (int*)(ws + 13306496);         //      1,024 B
    int*    perm     = (int*)(ws + 13307520);         //  6,400,000 B
    // extended region (only used when ws_size permits)
    int4*   hdr      = (int4*)(ws + 19707520);        // 25,600,000 B
    __bf16* fijb     = (__bf16*)(ws + 45307520);      // 102,400,000 B
    const size_t NEED_BIG = 45307520 + 102400000;     // 147,707,520 B

    const bool big = (ws_size >= NEED_BIG);
    float* agg = out;

    hipMemsetAsync(agg, 0, (size_t)N_ATOMS * FDIM * sizeof(float), stream);
    hipMemsetAsync(count, 0, N_ATOMS * sizeof(int), stream);

    hist_kernel<<<(N_EDGES + 255) / 256, 256, 0, stream>>>(dst, count);
    scan_chunk_kernel<<<NCH, 256, 0, stream>>>(count, chunksum);
    scan_base_kernel<<<1, 256, 0, stream>>>(chunksum);
    scan_apply_kernel<<<NCH, 256, 0, stream>>>(count, chunksum, cursor);
    scatter_kernel<<<(N_EDGES + 255) / 256, 256, 0, stream>>>(dst, cursor, perm);

    pack_b_kernel<<<(4096 + 255) / 256, 256, 0, stream>>>(W_f1, w1p, NB, 1);
    pack_b_kernel<<<(16384 + 255) / 256, 256, 0, stream>>>(W_f2, w2p, 128, 4);
    pack_b_kernel<<<(16384 + 255) / 256, 256, 0, stream>>>(W_in2f, winp, 128, 4);
    pack_b_kernel<<<(16384 + 255) / 256, 256, 0, stream>>>(W_out, woutp, 128, 4);

    if (big) {
        cvt_fij_kernel<<<(N_EDGES * 4 + 255) / 256, 256, 0, stream>>>(fij, fijb);
        hdr_kernel<<<(N_EDGES + 255) / 256, 256, 0, stream>>>(perm, src, dst, rij, hdr);
    }

    // x = feat @ W_in2f  -> xb (bf16, permuted)
    node_mfma_kernel<<<(N_ATOMS / 16 + 7) / 8, 512, 0, stream>>>(
        feat, winp, nullptr, xb, nullptr, 0);

    if (big) {
        edge_kernel<true><<<NBLK, 512, 0, stream>>>(
            fij, rij, src, dst, perm, hdr, fijb, w1p, b_f1, w2p, b_f2, xb, agg);
    } else {
        edge_kernel<false><<<NBLK, 512, 0, stream>>>(
            fij, rij, src, dst, perm, hdr, fijb, w1p, b_f1, w2p, b_f2, xb, agg);
    }

    // out = swish(agg @ W_out + b_out)  (in-place per 16-row tile)
    node_mfma_kernel<<<(N_ATOMS / 16 + 7) / 8, 512, 0, stream>>>(
        agg, woutp, b_out, nullptr, out, 1);
}

// Round 16
// 686.518 us; speedup vs baseline: 1.0575x; 1.0575x over previous
//
#include <hip/hip_runtime.h>
#include <hip/hip_bf16.h>
#include <math.h>

#define N_ATOMS 50000
#define N_EDGES 1600000
#define FDIM 128
#define NB 25
#define CUTOFF_F 5.0f
#define PI_OVER_CUTOFF 0.6283185307179586f
#define NCH 196   // scan chunks of 256
#define NBLK 512  // persistent blocks for edge kernel

typedef __bf16 bf16x8 __attribute__((ext_vector_type(8)));
typedef float f32x4 __attribute__((ext_vector_type(4)));

__device__ __forceinline__ float swish_f(float v) {
    return v / (1.0f + __expf(-v));
}

// XOR swizzle on 16B slots (for 256B-stride hs rows).
#define SWZ(row) ((((row) & 7) ^ (((row) >> 3) & 1)) << 4)

// ---------------- sort-by-dst machinery ----------------

__global__ void hist_kernel(const int* __restrict__ dst, int* __restrict__ count) {
    int i = blockIdx.x * 256 + threadIdx.x;
    if (i < N_EDGES) atomicAdd(&count[dst[i]], 1);
}

__global__ __launch_bounds__(256) void scan_chunk_kernel(
    const int* __restrict__ count, int* __restrict__ chunksum)
{
    __shared__ int red[256];
    const int t = threadIdx.x;
    const int i = blockIdx.x * 256 + t;
    red[t] = (i < N_ATOMS) ? count[i] : 0;
    __syncthreads();
    for (int o = 128; o > 0; o >>= 1) {
        if (t < o) red[t] += red[t + o];
        __syncthreads();
    }
    if (t == 0) chunksum[blockIdx.x] = red[0];
}

__global__ __launch_bounds__(256) void scan_base_kernel(int* __restrict__ chunksum) {
    __shared__ int sa[256], sb[256];
    const int t = threadIdx.x;
    int v = (t < NCH) ? chunksum[t] : 0;
    sa[t] = v;
    __syncthreads();
    int* cur = sa; int* nxt = sb;
    for (int o = 1; o < 256; o <<= 1) {
        int val = cur[t];
        if (t >= o) val += cur[t - o];
        nxt[t] = val;
        __syncthreads();
        int* tmp = cur; cur = nxt; nxt = tmp;
    }
    if (t < NCH) chunksum[t] = cur[t] - v;   // exclusive
}

__global__ __launch_bounds__(256) void scan_apply_kernel(
    const int* __restrict__ count, const int* __restrict__ chunksum,
    int* __restrict__ cursor)
{
    __shared__ int sa[256], sb[256];
    const int t = threadIdx.x;
    const int i = blockIdx.x * 256 + t;
    int v = (i < N_ATOMS) ? count[i] : 0;
    sa[t] = v;
    __syncthreads();
    int* cur = sa; int* nxt = sb;
    for (int o = 1; o < 256; o <<= 1) {
        int val = cur[t];
        if (t >= o) val += cur[t - o];
        nxt[t] = val;
        __syncthreads();
        int* tmp = cur; cur = nxt; nxt = tmp;
    }
    if (i < N_ATOMS) cursor[i] = chunksum[blockIdx.x] + cur[t] - v;  // exclusive
}

// scatter fused with header build: hdr[p] = {src, dst, C(rij), e}
__global__ void scatter_kernel(const int* __restrict__ src, const int* __restrict__ dst,
                               const float* __restrict__ rij,
                               int* __restrict__ cursor, int4* __restrict__ hdr)
{
    int i = blockIdx.x * 256 + threadIdx.x;
    if (i < N_EDGES) {
        int d = dst[i];
        int p = atomicAdd(&cursor[d], 1);
        float rr = rij[i];
        float C = (rr < CUTOFF_F) ? 0.5f * (__cosf(rr * PI_OVER_CUTOFF) + 1.0f) : 0.0f;
        int4 h;
        h.x = src[i];
        h.y = d;
        h.z = __float_as_int(C);
        h.w = i;
        hdr[p] = h;
    }
}

// ---------------- pre-pass: fij -> bf16 padded rows in SORTED order ----------------
// fijb[i*32 + k] = bf16(fij[hdr[i].w * 25 + k]) for k<25, else 0.

__global__ __launch_bounds__(256) void cvt_sorted_kernel(
    const int4* __restrict__ hdr, const float* __restrict__ fij,
    __bf16* __restrict__ fijb)
{
    int tid = blockIdx.x * 256 + threadIdx.x;   // one thread per quarter-row
    if (tid >= N_EDGES * 4) return;
    int q = tid & 3;
    int i = tid >> 2;
    int e = hdr[i].w;
    const float* fp = fij + (size_t)e * NB;
    bf16x8 o;
    #pragma unroll
    for (int j = 0; j < 8; ++j) {
        int k = (q << 3) + j;
        o[j] = (k < NB) ? (__bf16)fp[k] : (__bf16)0.0f;
    }
    *(bf16x8*)&fijb[((size_t)i << 5) + (q << 3)] = o;
}

// ---------------- weight packing ----------------

__global__ void pack_b_kernel(const float* __restrict__ W, __bf16* __restrict__ out,
                              int K_eff, int KS)
{
    int idx = blockIdx.x * 256 + threadIdx.x;
    int total = KS * 8 * 64 * 8;
    if (idx >= total) return;
    int j  = idx & 7;
    int l  = (idx >> 3) & 63;
    int n  = (idx >> 9) & 7;
    int ks = idx >> 12;
    int k   = ks * 32 + ((l >> 4) << 3) + j;
    int col = (n << 4) + (l & 15);
    float v = (k < K_eff) ? W[k * FDIM + col] : 0.0f;
    out[idx] = (__bf16)v;
}

// ---------------- MFMA node GEMM (r12-proven) ----------------

__global__ __launch_bounds__(512, 2) void node_mfma_kernel(
    const float* __restrict__ A, const __bf16* __restrict__ wp,
    const float* __restrict__ bias,
    __bf16* __restrict__ out_bf, float* __restrict__ out_f32,
    int do_swish)
{
    __shared__ __bf16 ws_[16384];   // 32 KB packed B

    const int t = threadIdx.x;
    const int l = t & 63;
    const int w = t >> 6;
    const int lrow = l & 15;
    const int kgrp = l >> 4;

    {
        const int4* g = (const int4*)wp;
        int4* s = (int4*)ws_;
        for (int i = t; i < 2048; i += 512) s[i] = g[i];
    }
    float br[8];
    #pragma unroll
    for (int n = 0; n < 8; ++n) br[n] = bias ? bias[(n << 4) + lrow] : 0.0f;
    __syncthreads();

    const int tile = blockIdx.x * 8 + w;
    if (tile >= N_ATOMS / 16) return;
    const int row0 = tile << 4;

    bf16x8 af[4];
    const float* ap = A + (size_t)(row0 + lrow) * FDIM + (kgrp << 3);
    #pragma unroll
    for (int ks = 0; ks < 4; ++ks) {
        float4 lo = *(const float4*)(ap + (ks << 5));
        float4 hi = *(const float4*)(ap + (ks << 5) + 4);
        af[ks][0] = (__bf16)lo.x; af[ks][1] = (__bf16)lo.y;
        af[ks][2] = (__bf16)lo.z; af[ks][3] = (__bf16)lo.w;
        af[ks][4] = (__bf16)hi.x; af[ks][5] = (__bf16)hi.y;
        af[ks][6] = (__bf16)hi.z; af[ks][7] = (__bf16)hi.w;
    }

    const f32x4 zero = {0.f, 0.f, 0.f, 0.f};
    f32x4 acc[8];
    #pragma unroll
    for (int n = 0; n < 8; ++n) acc[n] = zero;

    #pragma unroll
    for (int ks = 0; ks < 4; ++ks) {
        bf16x8 bfr[8];
        #pragma unroll
        for (int n = 0; n < 8; ++n)
            bfr[n] = *(const bf16x8*)((const char*)ws_ + (((ks << 3) + n) << 10) + (l << 4));
        #pragma unroll
        for (int n = 0; n < 8; ++n)
            acc[n] = __builtin_amdgcn_mfma_f32_16x16x32_bf16(af[ks], bfr[n], acc[n], 0, 0, 0);
    }

    if (out_bf) {
        #pragma unroll
        for (int r = 0; r < 4; ++r) {
            bf16x8 o;
            #pragma unroll
            for (int n = 0; n < 8; ++n) {
                float v = acc[n][r] + br[n];
                if (do_swish) v = swish_f(v);
                o[n] = (__bf16)v;
            }
            *(bf16x8*)&out_bf[(size_t)(row0 + (kgrp << 2) + r) * FDIM + (lrow << 3)] = o;
        }
    } else {
        #pragma unroll
        for (int r = 0; r < 4; ++r) {
            int orow = row0 + (kgrp << 2) + r;
            #pragma unroll
            for (int n = 0; n < 8; ++n) {
                float v = acc[n][r] + br[n];
                if (do_swish) v = swish_f(v);
                out_f32[(size_t)orow * FDIM + (n << 4) + lrow] = v;
            }
        }
    }
}

// ---------------- persistent-wave MFMA edge kernel ----------------
// Front-end is pure streaming: hdr and fijb are both indexed by the loop
// counter (sorted order) — no dependent gathers. xv issued 2 GEMMs early.
// Back-end (GEMM1/GEMM2/uni+run-compressed atomics) = r12-proven.

struct TR {
    bf16x8 a;            // fij A-fragment (bf16)
    int se, de;          // own edge src/dst
    float Cf;            // own edge cutoff factor
};

__global__ __launch_bounds__(512, 2) void edge_kernel(
    const int4* __restrict__ hdr, const __bf16* __restrict__ fijb,
    const __bf16* __restrict__ w1p, const float* __restrict__ b1,
    const __bf16* __restrict__ w2p, const float* __restrict__ b2,
    const __bf16* __restrict__ xb, float* __restrict__ agg)
{
    __shared__ __bf16 w2s[16384];       // 32 KB: W2 B-fragments
    __shared__ __bf16 hs[8][16 * 128];  // 32 KB: per-wave H tiles

    const int t = threadIdx.x;
    const int l = t & 63;
    const int w = t >> 6;               // 0..7
    const int lrow = l & 15;
    const int kgrp = l >> 4;

    {
        const int4* g2 = (const int4*)w2p;
        int4* s2 = (int4*)w2s;
        for (int i = t; i < 2048; i += 512) s2[i] = g2[i];
    }

    bf16x8 w1f[8];
    float b1r[8], b2r[8];
    #pragma unroll
    for (int n = 0; n < 8; ++n) {
        w1f[n] = *(const bf16x8*)(w1p + (((n << 6) + l) << 3));
        b1r[n] = b1[(n << 4) + lrow];
        b2r[n] = b2[(n << 4) + lrow];
    }
    __syncthreads();   // w2s ready; last barrier in the kernel

    __bf16* hw = hs[w];
    const f32x4 zero = {0.f, 0.f, 0.f, 0.f};

    const int gw = blockIdx.x * 8 + w;
    const int NW = NBLK * 8;
    const int NT = N_EDGES / 16;
    if (gw >= NT) return;

    TR cur, nxt;
    {
        int4 h = hdr[((size_t)gw << 4) + lrow];
        cur.a = *(const bf16x8*)&fijb[(((size_t)(gw << 4) + lrow) << 5) + (kgrp << 3)];
        cur.se = h.x; cur.de = h.y; cur.Cf = __int_as_float(h.z);
    }

    for (int tb = gw; tb < NT; tb += NW) {
        // ---- issue next tile's loads: addresses are pure functions of tb ----
        int nb = tb + NW; nb = (nb < NT) ? nb : (NT - 1);
        int4 hN = hdr[((size_t)nb << 4) + lrow];
        bf16x8 aN = *(const bf16x8*)&fijb[(((size_t)(nb << 4) + lrow) << 5) + (kgrp << 3)];

        // ---- epilogue prep: shfl headers + issue xv loads early ----
        int se4[4], de4[4]; float Cf[4];
        #pragma unroll
        for (int r = 0; r < 4; ++r) {
            se4[r] = __shfl(cur.se, (kgrp << 2) + r);
            Cf[r]  = __shfl(cur.Cf, (kgrp << 2) + r);
            de4[r] = __shfl(cur.de, (kgrp << 2) + r);
        }
        bf16x8 xv4[4];
        #pragma unroll
        for (int r = 0; r < 4; ++r)
            xv4[r] = *(const bf16x8*)&xb[(size_t)se4[r] * FDIM + (lrow << 3)];

        // ---- GEMM1: H = swish(fij_pad @ W1 + b1) -> hw (wave-local) ----
        #pragma unroll
        for (int n = 0; n < 8; ++n) {
            f32x4 h = __builtin_amdgcn_mfma_f32_16x16x32_bf16(cur.a, w1f[n], zero, 0, 0, 0);
            #pragma unroll
            for (int r = 0; r < 4; ++r) {
                int hrow = (kgrp << 2) + r;
                float hv = swish_f(h[r] + b1r[n]);
                int byte = (hrow << 8) + (((n << 4) + lrow) << 1);
                byte ^= SWZ(hrow);
                *(__bf16*)((char*)hw + byte) = (__bf16)hv;
            }
        }
        // no barrier: hw is wave-local (same-wave DS ops are ordered)

        // ---- GEMM2: Wfilt = H @ W2 (B-frags batched from LDS) ----
        f32x4 acc[8];
        #pragma unroll
        for (int n = 0; n < 8; ++n) acc[n] = zero;

        #pragma unroll
        for (int ks = 0; ks < 4; ++ks) {
            int byte = (lrow << 8) + (ks << 6) + (kgrp << 4);
            byte ^= SWZ(lrow);
            bf16x8 a2 = *(const bf16x8*)((const char*)hw + byte);
            bf16x8 bfr[8];
            #pragma unroll
            for (int n = 0; n < 8; ++n)
                bfr[n] = *(const bf16x8*)((const char*)w2s + (((ks << 3) + n) << 10) + (l << 4));
            #pragma unroll
            for (int n = 0; n < 8; ++n)
                acc[n] = __builtin_amdgcn_mfma_f32_16x16x32_bf16(a2, bfr[n], acc[n], 0, 0, 0);
        }

        // ---- Epilogue: uni fast path + run-compressed atomics (r12-proven) ----
        int d0 = __shfl(cur.de, 0);
        bool uni = __all(cur.de == d0);

        if (uni) {
            const size_t dbase = (size_t)d0 * FDIM;
            #pragma unroll
            for (int n = 0; n < 8; ++n) {
                float s = 0.f;
                #pragma unroll
                for (int r = 0; r < 4; ++r)
                    s += (float)xv4[r][n] * (acc[n][r] + b2r[n]) * Cf[r];
                s += __shfl_xor(s, 16);
                s += __shfl_xor(s, 32);
                if (kgrp == 0) unsafeAtomicAdd(&agg[dbase + (n << 4) + lrow], s);
            }
        } else {
            const bool brk0 = (de4[0] != de4[1]);
            const bool brk1 = (de4[1] != de4[2]);
            const bool brk2 = (de4[2] != de4[3]);
            #pragma unroll
            for (int n = 0; n < 8; ++n) {
                int col = (n << 4) + lrow;
                float m[4];
                #pragma unroll
                for (int r = 0; r < 4; ++r)
                    m[r] = (float)xv4[r][n] * (acc[n][r] + b2r[n]) * Cf[r];
                float run = m[0];
                if (brk0) { unsafeAtomicAdd(&agg[(size_t)de4[0] * FDIM + col], run); run = 0.f; }
                run += m[1];
                if (brk1) { unsafeAtomicAdd(&agg[(size_t)de4[1] * FDIM + col], run); run = 0.f; }
                run += m[2];
                if (brk2) { unsafeAtomicAdd(&agg[(size_t)de4[2] * FDIM + col], run); run = 0.f; }
                run += m[3];
                unsafeAtomicAdd(&agg[(size_t)de4[3] * FDIM + col], run);
            }
        }

        nxt.a = aN; nxt.se = hN.x; nxt.de = hN.y; nxt.Cf = __int_as_float(hN.z);
        cur = nxt;
    }
}

extern "C" void kernel_launch(void* const* d_in, const int* in_sizes, int n_in,
                              void* d_out, int out_size, void* d_ws, size_t ws_size,
                              hipStream_t stream)
{
    const float* feat   = (const float*)d_in[0];
    const float* fij    = (const float*)d_in[1];
    const float* rij    = (const float*)d_in[2];
    const int*   src    = (const int*)d_in[3];
    const int*   dst    = (const int*)d_in[4];
    const float* W_in2f = (const float*)d_in[5];
    const float* W_f1   = (const float*)d_in[6];
    const float* b_f1   = (const float*)d_in[7];
    const float* W_f2   = (const float*)d_in[8];
    const float* b_f2   = (const float*)d_in[9];
    const float* W_out  = (const float*)d_in[10];
    const float* b_out  = (const float*)d_in[11];
    float* out = (float*)d_out;

    // ws layout, total 141,307,520 B (< r15-proven 147,707,520 B watermark)
    char* ws = (char*)d_ws;
    __bf16* xb       = (__bf16*)ws;                   // 12,800,000 B
    __bf16* w1p      = (__bf16*)(ws + 12800000);      //      8,192 B
    __bf16* w2p      = (__bf16*)(ws + 12808192);      //     32,768 B
    __bf16* winp     = (__bf16*)(ws + 12840960);      //     32,768 B
    __bf16* woutp    = (__bf16*)(ws + 12873728);      //     32,768 B
    int*    cursor   = (int*)(ws + 12906496);         //    200,000 B
    int*    count    = (int*)(ws + 13106496);         //    200,000 B
    int*    chunksum = (int*)(ws + 13306496);         //      1,024 B
    int4*   hdr      = (int4*)(ws + 13307520);        // 25,600,000 B
    __bf16* fijb     = (__bf16*)(ws + 38907520);      // 102,400,000 B
    float*  agg      = out;                           // accumulate into d_out

    hipMemsetAsync(agg, 0, (size_t)N_ATOMS * FDIM * sizeof(float), stream);
    hipMemsetAsync(count, 0, N_ATOMS * sizeof(int), stream);

    hist_kernel<<<(N_EDGES + 255) / 256, 256, 0, stream>>>(dst, count);
    scan_chunk_kernel<<<NCH, 256, 0, stream>>>(count, chunksum);
    scan_base_kernel<<<1, 256, 0, stream>>>(chunksum);
    scan_apply_kernel<<<NCH, 256, 0, stream>>>(count, chunksum, cursor);
    scatter_kernel<<<(N_EDGES + 255) / 256, 256, 0, stream>>>(src, dst, rij, cursor, hdr);

    cvt_sorted_kernel<<<(N_EDGES * 4 + 255) / 256, 256, 0, stream>>>(hdr, fij, fijb);

    pack_b_kernel<<<(4096 + 255) / 256, 256, 0, stream>>>(W_f1, w1p, NB, 1);
    pack_b_kernel<<<(16384 + 255) / 256, 256, 0, stream>>>(W_f2, w2p, 128, 4);
    pack_b_kernel<<<(16384 + 255) / 256, 256, 0, stream>>>(W_in2f, winp, 128, 4);
    pack_b_kernel<<<(16384 + 255) / 256, 256, 0, stream>>>(W_out, woutp, 128, 4);

    // x = feat @ W_in2f  -> xb (bf16, permuted)
    node_mfma_kernel<<<(N_ATOMS / 16 + 7) / 8, 512, 0, stream>>>(
        feat, winp, nullptr, xb, nullptr, 0);

    edge_kernel<<<NBLK, 512, 0, stream>>>(
        hdr, fijb, w1p, b_f1, w2p, b_f2, xb, agg);

    // out = swish(agg @ W_out + b_out)  (in-place per 16-row tile)
    node_mfma_kernel<<<(N_ATOMS / 16 + 7) / 8, 512, 0, stream>>>(
        agg, woutp, b_out, nullptr, out, 1);
}

// Round 17
// 616.908 us; speedup vs baseline: 1.1768x; 1.1128x over previous
//
#include <hip/hip_runtime.h>
#include <hip/hip_bf16.h>
#include <math.h>

#define N_ATOMS 50000
#define N_EDGES 1600000
#define FDIM 128
#define NB 25
#define CUTOFF_F 5.0f
#define PI_OVER_CUTOFF 0.6283185307179586f
#define NCH 196   // scan chunks of 256
#define NBLK 512  // persistent blocks for edge kernel

typedef __bf16 bf16x8 __attribute__((ext_vector_type(8)));
typedef float f32x4 __attribute__((ext_vector_type(4)));

__device__ __forceinline__ float swish_f(float v) {
    return v / (1.0f + __expf(-v));
}

// XOR swizzle on 16B slots (for 256B-stride hs rows).
#define SWZ(row) ((((row) & 7) ^ (((row) >> 3) & 1)) << 4)

// ---------------- sort-by-dst machinery (r12-proven) ----------------

__global__ void hist_kernel(const int* __restrict__ dst, int* __restrict__ count) {
    int i = blockIdx.x * 256 + threadIdx.x;
    if (i < N_EDGES) atomicAdd(&count[dst[i]], 1);
}

__global__ __launch_bounds__(256) void scan_chunk_kernel(
    const int* __restrict__ count, int* __restrict__ chunksum)
{
    __shared__ int red[256];
    const int t = threadIdx.x;
    const int i = blockIdx.x * 256 + t;
    red[t] = (i < N_ATOMS) ? count[i] : 0;
    __syncthreads();
    for (int o = 128; o > 0; o >>= 1) {
        if (t < o) red[t] += red[t + o];
        __syncthreads();
    }
    if (t == 0) chunksum[blockIdx.x] = red[0];
}

__global__ __launch_bounds__(256) void scan_base_kernel(int* __restrict__ chunksum) {
    __shared__ int sa[256], sb[256];
    const int t = threadIdx.x;
    int v = (t < NCH) ? chunksum[t] : 0;
    sa[t] = v;
    __syncthreads();
    int* cur = sa; int* nxt = sb;
    for (int o = 1; o < 256; o <<= 1) {
        int val = cur[t];
        if (t >= o) val += cur[t - o];
        nxt[t] = val;
        __syncthreads();
        int* tmp = cur; cur = nxt; nxt = tmp;
    }
    if (t < NCH) chunksum[t] = cur[t] - v;   // exclusive
}

__global__ __launch_bounds__(256) void scan_apply_kernel(
    const int* __restrict__ count, const int* __restrict__ chunksum,
    int* __restrict__ cursor)
{
    __shared__ int sa[256], sb[256];
    const int t = threadIdx.x;
    const int i = blockIdx.x * 256 + t;
    int v = (i < N_ATOMS) ? count[i] : 0;
    sa[t] = v;
    __syncthreads();
    int* cur = sa; int* nxt = sb;
    for (int o = 1; o < 256; o <<= 1) {
        int val = cur[t];
        if (t >= o) val += cur[t - o];
        nxt[t] = val;
        __syncthreads();
        int* tmp = cur; cur = nxt; nxt = tmp;
    }
    if (i < N_ATOMS) cursor[i] = chunksum[blockIdx.x] + cur[t] - v;  // exclusive
}

__global__ void scatter_kernel(const int* __restrict__ dst, int* __restrict__ cursor,
                               int* __restrict__ perm) {
    int i = blockIdx.x * 256 + threadIdx.x;
    if (i < N_EDGES) {
        int d = dst[i];
        int p = atomicAdd(&cursor[d], 1);
        perm[p] = i;
    }
}

// ---------------- weight packing ----------------

__global__ void pack_b_kernel(const float* __restrict__ W, __bf16* __restrict__ out,
                              int K_eff, int KS)
{
    int idx = blockIdx.x * 256 + threadIdx.x;
    int total = KS * 8 * 64 * 8;
    if (idx >= total) return;
    int j  = idx & 7;
    int l  = (idx >> 3) & 63;
    int n  = (idx >> 9) & 7;
    int ks = idx >> 12;
    int k   = ks * 32 + ((l >> 4) << 3) + j;
    int col = (n << 4) + (l & 15);
    float v = (k < K_eff) ? W[k * FDIM + col] : 0.0f;
    out[idx] = (__bf16)v;
}

// ---------------- MFMA node GEMM (r12-proven) ----------------

__global__ __launch_bounds__(512, 2) void node_mfma_kernel(
    const float* __restrict__ A, const __bf16* __restrict__ wp,
    const float* __restrict__ bias,
    __bf16* __restrict__ out_bf, float* __restrict__ out_f32,
    int do_swish)
{
    __shared__ __bf16 ws_[16384];   // 32 KB packed B

    const int t = threadIdx.x;
    const int l = t & 63;
    const int w = t >> 6;
    const int lrow = l & 15;
    const int kgrp = l >> 4;

    {
        const int4* g = (const int4*)wp;
        int4* s = (int4*)ws_;
        for (int i = t; i < 2048; i += 512) s[i] = g[i];
    }
    float br[8];
    #pragma unroll
    for (int n = 0; n < 8; ++n) br[n] = bias ? bias[(n << 4) + lrow] : 0.0f;
    __syncthreads();

    const int tile = blockIdx.x * 8 + w;
    if (tile >= N_ATOMS / 16) return;
    const int row0 = tile << 4;

    bf16x8 af[4];
    const float* ap = A + (size_t)(row0 + lrow) * FDIM + (kgrp << 3);
    #pragma unroll
    for (int ks = 0; ks < 4; ++ks) {
        float4 lo = *(const float4*)(ap + (ks << 5));
        float4 hi = *(const float4*)(ap + (ks << 5) + 4);
        af[ks][0] = (__bf16)lo.x; af[ks][1] = (__bf16)lo.y;
        af[ks][2] = (__bf16)lo.z; af[ks][3] = (__bf16)lo.w;
        af[ks][4] = (__bf16)hi.x; af[ks][5] = (__bf16)hi.y;
        af[ks][6] = (__bf16)hi.z; af[ks][7] = (__bf16)hi.w;
    }

    const f32x4 zero = {0.f, 0.f, 0.f, 0.f};
    f32x4 acc[8];
    #pragma unroll
    for (int n = 0; n < 8; ++n) acc[n] = zero;

    #pragma unroll
    for (int ks = 0; ks < 4; ++ks) {
        bf16x8 bfr[8];
        #pragma unroll
        for (int n = 0; n < 8; ++n)
            bfr[n] = *(const bf16x8*)((const char*)ws_ + (((ks << 3) + n) << 10) + (l << 4));
        #pragma unroll
        for (int n = 0; n < 8; ++n)
            acc[n] = __builtin_amdgcn_mfma_f32_16x16x32_bf16(af[ks], bfr[n], acc[n], 0, 0, 0);
    }

    if (out_bf) {
        #pragma unroll
        for (int r = 0; r < 4; ++r) {
            bf16x8 o;
            #pragma unroll
            for (int n = 0; n < 8; ++n) {
                float v = acc[n][r] + br[n];
                if (do_swish) v = swish_f(v);
                o[n] = (__bf16)v;
            }
            *(bf16x8*)&out_bf[(size_t)(row0 + (kgrp << 2) + r) * FDIM + (lrow << 3)] = o;
        }
    } else {
        #pragma unroll
        for (int r = 0; r < 4; ++r) {
            int orow = row0 + (kgrp << 2) + r;
            #pragma unroll
            for (int n = 0; n < 8; ++n) {
                float v = acc[n][r] + br[n];
                if (do_swish) v = swish_f(v);
                out_f32[(size_t)orow * FDIM + (n << 4) + lrow] = v;
            }
        }
    }
}

// ---------------- persistent-wave MFMA edge kernel ----------------
// r12 structure with ONE change: xv loads are the FIRST vmem ops of each
// iteration (before next-tile gathers). With vmcnt FIFO semantics, the
// epilogue's xv wait is then vmcnt(~#gathers) instead of vmcnt(0) — the
// previous iteration's atomic RMWs never have to drain.

struct TileReg {
    float4 f0, f1;       // this lane's fij A-fragment data
    int   se_own, de_own;
    float rij_own;
};

__global__ __launch_bounds__(512, 2) void edge_kernel(
    const float* __restrict__ fij, const float* __restrict__ rij,
    const int* __restrict__ src, const int* __restrict__ dst,
    const int* __restrict__ perm,
    const __bf16* __restrict__ w1p, const float* __restrict__ b1,
    const __bf16* __restrict__ w2p, const float* __restrict__ b2,
    const __bf16* __restrict__ xb, float* __restrict__ agg)
{
    __shared__ __bf16 w2s[16384];       // 32 KB: W2 B-fragments
    __shared__ __bf16 hs[8][16 * 128];  // 32 KB: per-wave H tiles

    const int t = threadIdx.x;
    const int l = t & 63;
    const int w = t >> 6;               // 0..7
    const int lrow = l & 15;
    const int kgrp = l >> 4;

    {
        const int4* g2 = (const int4*)w2p;
        int4* s2 = (int4*)w2s;
        for (int i = t; i < 2048; i += 512) s2[i] = g2[i];
    }

    bf16x8 w1f[8];
    float b1r[8], b2r[8];
    #pragma unroll
    for (int n = 0; n < 8; ++n) {
        w1f[n] = *(const bf16x8*)(w1p + (((n << 6) + l) << 3));
        b1r[n] = b1[(n << 4) + lrow];
        b2r[n] = b2[(n << 4) + lrow];
    }
    __syncthreads();   // w2s ready; last barrier in the kernel

    __bf16* hw = hs[w];
    const f32x4 zero = {0.f, 0.f, 0.f, 0.f};

    const int gw = blockIdx.x * 8 + w;   // global wave id
    const int NW = NBLK * 8;
    const int NT = N_EDGES / 16;
    if (gw >= NT) return;

    #define GATHER(T, pv) do { \
        const float* fp_ = fij + (size_t)(pv) * NB; \
        if (kgrp < 3) { \
            T.f0 = *(const float4*)(fp_ + (kgrp << 3)); \
            T.f1 = *(const float4*)(fp_ + (kgrp << 3) + 4); \
        } else { \
            T.f0 = make_float4(fp_[24], 0.f, 0.f, 0.f); \
            T.f1 = make_float4(0.f, 0.f, 0.f, 0.f); \
        } \
        T.se_own = src[pv]; \
        T.de_own = dst[pv]; \
        T.rij_own = rij[pv]; \
    } while (0)

    TileReg cur, nxt;
    int pvB;
    {
        int pvA = perm[((size_t)gw << 4) + lrow];
        GATHER(cur, pvA);
        int i2 = gw + NW; i2 = (i2 < NT) ? i2 : (NT - 1);
        pvB = perm[((size_t)i2 << 4) + lrow];
    }

    for (int tb = gw; tb < NT; tb += NW) {
        // ---- (1) epilogue prep for CUR: shfls + xv loads FIRST (vmem head) ----
        float Cf_own = (cur.rij_own < CUTOFF_F)
                     ? 0.5f * (__cosf(cur.rij_own * PI_OVER_CUTOFF) + 1.0f) : 0.0f;
        int se4[4], de4[4]; float Cf[4];
        #pragma unroll
        for (int r = 0; r < 4; ++r) {
            se4[r] = __shfl(cur.se_own, (kgrp << 2) + r);
            Cf[r]  = __shfl(Cf_own, (kgrp << 2) + r);
            de4[r] = __shfl(cur.de_own, (kgrp << 2) + r);
        }
        bf16x8 xv4[4];
        #pragma unroll
        for (int r = 0; r < 4; ++r)
            xv4[r] = *(const bf16x8*)&xb[(size_t)se4[r] * FDIM + (lrow << 3)];

        // ---- (2) next-tile gathers AFTER xv (these pad xv's vmcnt slack) ----
        GATHER(nxt, pvB);
        int i3 = tb + 2 * NW; i3 = (i3 < NT) ? i3 : (NT - 1);
        pvB = perm[((size_t)i3 << 4) + lrow];

        // ---- (3) GEMM1: H = swish(fij_pad @ W1 + b1) -> hw (wave-local) ----
        bf16x8 a;
        a[0] = (__bf16)cur.f0.x; a[1] = (__bf16)cur.f0.y;
        a[2] = (__bf16)cur.f0.z; a[3] = (__bf16)cur.f0.w;
        a[4] = (__bf16)cur.f1.x; a[5] = (__bf16)cur.f1.y;
        a[6] = (__bf16)cur.f1.z; a[7] = (__bf16)cur.f1.w;

        #pragma unroll
        for (int n = 0; n < 8; ++n) {
            f32x4 h = __builtin_amdgcn_mfma_f32_16x16x32_bf16(a, w1f[n], zero, 0, 0, 0);
            #pragma unroll
            for (int r = 0; r < 4; ++r) {
                int hrow = (kgrp << 2) + r;
                float hv = swish_f(h[r] + b1r[n]);
                int byte = (hrow << 8) + (((n << 4) + lrow) << 1);
                byte ^= SWZ(hrow);
                *(__bf16*)((char*)hw + byte) = (__bf16)hv;
            }
        }
        // no barrier: hw is wave-local (same-wave DS ops are ordered)

        // ---- (4) GEMM2: Wfilt = H @ W2 (B-frags batched from LDS) ----
        f32x4 acc[8];
        #pragma unroll
        for (int n = 0; n < 8; ++n) acc[n] = zero;

        #pragma unroll
        for (int ks = 0; ks < 4; ++ks) {
            int byte = (lrow << 8) + (ks << 6) + (kgrp << 4);
            byte ^= SWZ(lrow);
            bf16x8 a2 = *(const bf16x8*)((const char*)hw + byte);
            bf16x8 bfr[8];
            #pragma unroll
            for (int n = 0; n < 8; ++n)
                bfr[n] = *(const bf16x8*)((const char*)w2s + (((ks << 3) + n) << 10) + (l << 4));
            #pragma unroll
            for (int n = 0; n < 8; ++n)
                acc[n] = __builtin_amdgcn_mfma_f32_16x16x32_bf16(a2, bfr[n], acc[n], 0, 0, 0);
        }

        // ---- (5) Epilogue: uni fast path + run-compressed atomics ----
        int d0 = __shfl(cur.de_own, 0);
        bool uni = __all(cur.de_own == d0);

        if (uni) {
            const size_t dbase = (size_t)d0 * FDIM;
            #pragma unroll
            for (int n = 0; n < 8; ++n) {
                float s = 0.f;
                #pragma unroll
                for (int r = 0; r < 4; ++r)
                    s += (float)xv4[r][n] * (acc[n][r] + b2r[n]) * Cf[r];
                s += __shfl_xor(s, 16);
                s += __shfl_xor(s, 32);
                if (kgrp == 0) unsafeAtomicAdd(&agg[dbase + (n << 4) + lrow], s);
            }
        } else {
            const bool brk0 = (de4[0] != de4[1]);
            const bool brk1 = (de4[1] != de4[2]);
            const bool brk2 = (de4[2] != de4[3]);
            #pragma unroll
            for (int n = 0; n < 8; ++n) {
                int col = (n << 4) + lrow;
                float m[4];
                #pragma unroll
                for (int r = 0; r < 4; ++r)
                    m[r] = (float)xv4[r][n] * (acc[n][r] + b2r[n]) * Cf[r];
                float run = m[0];
                if (brk0) { unsafeAtomicAdd(&agg[(size_t)de4[0] * FDIM + col], run); run = 0.f; }
                run += m[1];
                if (brk1) { unsafeAtomicAdd(&agg[(size_t)de4[1] * FDIM + col], run); run = 0.f; }
                run += m[2];
                if (brk2) { unsafeAtomicAdd(&agg[(size_t)de4[2] * FDIM + col], run); run = 0.f; }
                run += m[3];
                unsafeAtomicAdd(&agg[(size_t)de4[3] * FDIM + col], run);
            }
        }

        cur = nxt;
    }
    #undef GATHER
}

extern "C" void kernel_launch(void* const* d_in, const int* in_sizes, int n_in,
                              void* d_out, int out_size, void* d_ws, size_t ws_size,
                              hipStream_t stream)
{
    const float* feat   = (const float*)d_in[0];
    const float* fij    = (const float*)d_in[1];
    const float* rij    = (const float*)d_in[2];
    const int*   src    = (const int*)d_in[3];
    const int*   dst    = (const int*)d_in[4];
    const float* W_in2f = (const float*)d_in[5];
    const float* W_f1   = (const float*)d_in[6];
    const float* b_f1   = (const float*)d_in[7];
    const float* W_f2   = (const float*)d_in[8];
    const float* b_f2   = (const float*)d_in[9];
    const float* W_out  = (const float*)d_in[10];
    const float* b_out  = (const float*)d_in[11];
    float* out = (float*)d_out;

    // ws layout, total 19,707,520 B (r12-proven)
    char* ws = (char*)d_ws;
    __bf16* xb       = (__bf16*)ws;                   // 12,800,000 B
    __bf16* w1p      = (__bf16*)(ws + 12800000);      //      8,192 B
    __bf16* w2p      = (__bf16*)(ws + 12808192);      //     32,768 B
    __bf16* winp     = (__bf16*)(ws + 12840960);      //     32,768 B
    __bf16* woutp    = (__bf16*)(ws + 12873728);      //     32,768 B
    int*    cursor   = (int*)(ws + 12906496);         //    200,000 B
    int*    count    = (int*)(ws + 13106496);         //    200,000 B
    int*    chunksum = (int*)(ws + 13306496);         //      1,024 B
    int*    perm     = (int*)(ws + 13307520);         //  6,400,000 B
    float*  agg      = out;                           // accumulate into d_out

    hipMemsetAsync(agg, 0, (size_t)N_ATOMS * FDIM * sizeof(float), stream);
    hipMemsetAsync(count, 0, N_ATOMS * sizeof(int), stream);

    hist_kernel<<<(N_EDGES + 255) / 256, 256, 0, stream>>>(dst, count);
    scan_chunk_kernel<<<NCH, 256, 0, stream>>>(count, chunksum);
    scan_base_kernel<<<1, 256, 0, stream>>>(chunksum);
    scan_apply_kernel<<<NCH, 256, 0, stream>>>(count, chunksum, cursor);
    scatter_kernel<<<(N_EDGES + 255) / 256, 256, 0, stream>>>(dst, cursor, perm);

    pack_b_kernel<<<(4096 + 255) / 256, 256, 0, stream>>>(W_f1, w1p, NB, 1);
    pack_b_kernel<<<(16384 + 255) / 256, 256, 0, stream>>>(W_f2, w2p, 128, 4);
    pack_b_kernel<<<(16384 + 255) / 256, 256, 0, stream>>>(W_in2f, winp, 128, 4);
    pack_b_kernel<<<(16384 + 255) / 256, 256, 0, stream>>>(W_out, woutp, 128, 4);

    // x = feat @ W_in2f  -> xb (bf16, permuted)
    node_mfma_kernel<<<(N_ATOMS / 16 + 7) / 8, 512, 0, stream>>>(
        feat, winp, nullptr, xb, nullptr, 0);

    edge_kernel<<<NBLK, 512, 0, stream>>>(
        fij, rij, src, dst, perm, w1p, b_f1, w2p, b_f2, xb, agg);

    // out = swish(agg @ W_out + b_out)  (in-place per 16-row tile)
    node_mfma_kernel<<<(N_ATOMS / 16 + 7) / 8, 512, 0, stream>>>(
        agg, woutp, b_out, nullptr, out, 1);
}

// Round 18
// 451.601 us; speedup vs baseline: 1.6075x; 1.3660x over previous
//
#include <hip/hip_runtime.h>
#include <hip/hip_bf16.h>
#include <math.h>

#define N_ATOMS 50000
#define N_EDGES 1600000
#define FDIM 128
#define NB 25
#define CUTOFF_F 5.0f
#define PI_OVER_CUTOFF 0.6283185307179586f
#define NBLK 512  // persistent blocks for edge kernel
#define RB 196    // radix buckets = dst>>8 (50000>>8 -> 0..195)
#define P1B 782   // pass-1 blocks = ceil(1.6M / 2048)

typedef __bf16 bf16x8 __attribute__((ext_vector_type(8)));
typedef float f32x4 __attribute__((ext_vector_type(4)));

__device__ __forceinline__ float swish_f(float v) {
    // v * rcp(1+e^-v): v_rcp_f32 (~1ulp) instead of full-precision divide
    return v * __builtin_amdgcn_rcpf(1.0f + __expf(-v));
}

// XOR swizzle on 16B slots (for 256B-stride hs rows).
#define SWZ(row) ((((row) & 7) ^ (((row) >> 3) & 1)) << 4)

// ---------------- LDS-radix group-by-dst (zero global atomics) ----------------

// Pass 1a: per-block LDS histogram over dst>>8; emit packed (bucket<<11|rank)
// per edge and the per-(bucket,block) count matrix gh[k*P1B + b].
__global__ __launch_bounds__(256) void radix1_hist_kernel(
    const int* __restrict__ dst, int* __restrict__ ebkt, int* __restrict__ gh)
{
    __shared__ int lh[RB];
    const int t = threadIdx.x;
    const int b = blockIdx.x;
    for (int i = t; i < RB; i += 256) lh[i] = 0;
    __syncthreads();
    const int base = b * 2048;
    #pragma unroll
    for (int it = 0; it < 8; ++it) {
        int i = base + it * 256 + t;
        if (i < N_EDGES) {
            int bkt = dst[i] >> 8;
            int rank = atomicAdd(&lh[bkt], 1);   // LDS atomic
            ebkt[i] = (bkt << 11) | rank;        // rank <= 2047 fits 11 bits
        }
    }
    __syncthreads();
    for (int i = t; i < RB; i += 256) gh[i * P1B + b] = lh[i];
}

// Pass 1b: per-bucket exclusive scan over blocks (196 blocks, chunked H-S).
__global__ __launch_bounds__(256) void scan_buckets_kernel(
    const int* __restrict__ gh, int* __restrict__ off, int* __restrict__ bt)
{
    __shared__ int sa[256], sb[256];
    const int k = blockIdx.x;
    const int t = threadIdx.x;
    const int base = k * P1B;
    int v[4]; int s = 0;
    #pragma unroll
    for (int j = 0; j < 4; ++j) {
        int b = t * 4 + j;
        v[j] = (b < P1B) ? gh[base + b] : 0;
        s += v[j];
    }
    sa[t] = s;
    __syncthreads();
    int* cur = sa; int* nxt = sb;
    for (int o = 1; o < 256; o <<= 1) {
        int val = cur[t];
        if (t >= o) val += cur[t - o];
        nxt[t] = val;
        __syncthreads();
        int* tmp = cur; cur = nxt; nxt = tmp;
    }
    int run = cur[t] - s;                 // exclusive prefix for this thread
    #pragma unroll
    for (int j = 0; j < 4; ++j) {
        int b = t * 4 + j;
        if (b < P1B) off[base + b] = run;
        run += v[j];
    }
    if (t == 255) bt[k] = cur[t];         // bucket total
}

// Pass 1b': exclusive scan of 196 bucket totals (in place) + sentinel total.
__global__ __launch_bounds__(256) void scan_base_kernel(int* __restrict__ bt) {
    __shared__ int sa[256], sb[256];
    const int t = threadIdx.x;
    int v = (t < RB) ? bt[t] : 0;
    sa[t] = v;
    __syncthreads();
    int* cur = sa; int* nxt = sb;
    for (int o = 1; o < 256; o <<= 1) {
        int val = cur[t];
        if (t >= o) val += cur[t - o];
        nxt[t] = val;
        __syncthreads();
        int* tmp = cur; cur = nxt; nxt = tmp;
    }
    if (t < RB) bt[t] = cur[t] - v;       // exclusive
    if (t == RB - 1) bt[RB] = cur[t];     // total = N_EDGES
}

// Pass 1c: place edge ids into bucket-partitioned ebuf1.
__global__ __launch_bounds__(256) void radix1_place_kernel(
    const int* __restrict__ ebkt, const int* __restrict__ off,
    const int* __restrict__ bstart, int* __restrict__ ebuf1)
{
    __shared__ int obs[RB];
    const int t = threadIdx.x;
    const int b = blockIdx.x;
    if (t < RB) obs[t] = bstart[t] + off[t * P1B + b];
    __syncthreads();
    const int base = b * 2048;
    #pragma unroll
    for (int it = 0; it < 8; ++it) {
        int i = base + it * 256 + t;
        if (i < N_EDGES) {
            int p = ebkt[i];
            ebuf1[obs[p >> 11] + (p & 2047)] = i;
        }
    }
}

// Pass 2: within-bucket exact group-by dst (bin = dst&255) via LDS hist+scan.
__global__ __launch_bounds__(1024) void radix2_kernel(
    const int* __restrict__ ebuf1, const int* __restrict__ dst,
    const int* __restrict__ bstart, int* __restrict__ perm)
{
    __shared__ int lh2[256], sa[256], sb[256], cur2[256];
    const int t = threadIdx.x;
    const int k = blockIdx.x;
    const int start = bstart[k];
    const int end = bstart[k + 1];
    if (t < 256) lh2[t] = 0;
    __syncthreads();
    for (int i = start + t; i < end; i += 1024) {
        int e = ebuf1[i];
        atomicAdd(&lh2[dst[e] & 255], 1);   // LDS atomic
    }
    __syncthreads();
    if (t < 256) sa[t] = lh2[t];
    __syncthreads();
    int* cur = sa; int* nxt = sb;
    for (int o = 1; o < 256; o <<= 1) {
        if (t < 256) {
            int val = cur[t];
            if (t >= o) val += cur[t - o];
            nxt[t] = val;
        }
        __syncthreads();
        int* tmp = cur; cur = nxt; nxt = tmp;
    }
    if (t < 256) cur2[t] = cur[t] - lh2[t];   // exclusive bin start
    __syncthreads();
    for (int i = start + t; i < end; i += 1024) {
        int e = ebuf1[i];
        int r = atomicAdd(&cur2[dst[e] & 255], 1);   // LDS cursor
        perm[start + r] = e;
    }
}

// ---------------- weight packing ----------------

__global__ void pack_b_kernel(const float* __restrict__ W, __bf16* __restrict__ out,
                              int K_eff, int KS)
{
    int idx = blockIdx.x * 256 + threadIdx.x;
    int total = KS * 8 * 64 * 8;
    if (idx >= total) return;
    int j  = idx & 7;
    int l  = (idx >> 3) & 63;
    int n  = (idx >> 9) & 7;
    int ks = idx >> 12;
    int k   = ks * 32 + ((l >> 4) << 3) + j;
    int col = (n << 4) + (l & 15);
    float v = (k < K_eff) ? W[k * FDIM + col] : 0.0f;
    out[idx] = (__bf16)v;
}

// ---------------- MFMA node GEMM (r12-proven) ----------------

__global__ __launch_bounds__(512, 2) void node_mfma_kernel(
    const float* __restrict__ A, const __bf16* __restrict__ wp,
    const float* __restrict__ bias,
    __bf16* __restrict__ out_bf, float* __restrict__ out_f32,
    int do_swish)
{
    __shared__ __bf16 ws_[16384];   // 32 KB packed B

    const int t = threadIdx.x;
    const int l = t & 63;
    const int w = t >> 6;
    const int lrow = l & 15;
    const int kgrp = l >> 4;

    {
        const int4* g = (const int4*)wp;
        int4* s = (int4*)ws_;
        for (int i = t; i < 2048; i += 512) s[i] = g[i];
    }
    float br[8];
    #pragma unroll
    for (int n = 0; n < 8; ++n) br[n] = bias ? bias[(n << 4) + lrow] : 0.0f;
    __syncthreads();

    const int tile = blockIdx.x * 8 + w;
    if (tile >= N_ATOMS / 16) return;
    const int row0 = tile << 4;

    bf16x8 af[4];
    const float* ap = A + (size_t)(row0 + lrow) * FDIM + (kgrp << 3);
    #pragma unroll
    for (int ks = 0; ks < 4; ++ks) {
        float4 lo = *(const float4*)(ap + (ks << 5));
        float4 hi = *(const float4*)(ap + (ks << 5) + 4);
        af[ks][0] = (__bf16)lo.x; af[ks][1] = (__bf16)lo.y;
        af[ks][2] = (__bf16)lo.z; af[ks][3] = (__bf16)lo.w;
        af[ks][4] = (__bf16)hi.x; af[ks][5] = (__bf16)hi.y;
        af[ks][6] = (__bf16)hi.z; af[ks][7] = (__bf16)hi.w;
    }

    const f32x4 zero = {0.f, 0.f, 0.f, 0.f};
    f32x4 acc[8];
    #pragma unroll
    for (int n = 0; n < 8; ++n) acc[n] = zero;

    #pragma unroll
    for (int ks = 0; ks < 4; ++ks) {
        bf16x8 bfr[8];
        #pragma unroll
        for (int n = 0; n < 8; ++n)
            bfr[n] = *(const bf16x8*)((const char*)ws_ + (((ks << 3) + n) << 10) + (l << 4));
        #pragma unroll
        for (int n = 0; n < 8; ++n)
            acc[n] = __builtin_amdgcn_mfma_f32_16x16x32_bf16(af[ks], bfr[n], acc[n], 0, 0, 0);
    }

    if (out_bf) {
        #pragma unroll
        for (int r = 0; r < 4; ++r) {
            bf16x8 o;
            #pragma unroll
            for (int n = 0; n < 8; ++n) {
                float v = acc[n][r] + br[n];
                if (do_swish) v = swish_f(v);
                o[n] = (__bf16)v;
            }
            *(bf16x8*)&out_bf[(size_t)(row0 + (kgrp << 2) + r) * FDIM + (lrow << 3)] = o;
        }
    } else {
        #pragma unroll
        for (int r = 0; r < 4; ++r) {
            int orow = row0 + (kgrp << 2) + r;
            #pragma unroll
            for (int n = 0; n < 8; ++n) {
                float v = acc[n][r] + br[n];
                if (do_swish) v = swish_f(v);
                out_f32[(size_t)orow * FDIM + (n << 4) + lrow] = v;
            }
        }
    }
}

// ---------------- persistent-wave MFMA edge kernel (r17 structure) ----------------
// xv loads are the FIRST vmem ops of each iteration (vmcnt FIFO: epilogue's
// xv wait never drains the previous iteration's atomics).

struct TileReg {
    float4 f0, f1;       // this lane's fij A-fragment data
    int   se_own, de_own;
    float rij_own;
};

__global__ __launch_bounds__(512, 2) void edge_kernel(
    const float* __restrict__ fij, const float* __restrict__ rij,
    const int* __restrict__ src, const int* __restrict__ dst,
    const int* __restrict__ perm,
    const __bf16* __restrict__ w1p, const float* __restrict__ b1,
    const __bf16* __restrict__ w2p, const float* __restrict__ b2,
    const __bf16* __restrict__ xb, float* __restrict__ agg)
{
    __shared__ __bf16 w2s[16384];       // 32 KB: W2 B-fragments
    __shared__ __bf16 hs[8][16 * 128];  // 32 KB: per-wave H tiles

    const int t = threadIdx.x;
    const int l = t & 63;
    const int w = t >> 6;               // 0..7
    const int lrow = l & 15;
    const int kgrp = l >> 4;

    {
        const int4* g2 = (const int4*)w2p;
        int4* s2 = (int4*)w2s;
        for (int i = t; i < 2048; i += 512) s2[i] = g2[i];
    }

    bf16x8 w1f[8];
    float b1r[8], b2r[8];
    #pragma unroll
    for (int n = 0; n < 8; ++n) {
        w1f[n] = *(const bf16x8*)(w1p + (((n << 6) + l) << 3));
        b1r[n] = b1[(n << 4) + lrow];
        b2r[n] = b2[(n << 4) + lrow];
    }
    __syncthreads();   // w2s ready; last barrier in the kernel

    __bf16* hw = hs[w];
    const f32x4 zero = {0.f, 0.f, 0.f, 0.f};

    const int gw = blockIdx.x * 8 + w;   // global wave id
    const int NW = NBLK * 8;
    const int NT = N_EDGES / 16;
    if (gw >= NT) return;

    #define GATHER(T, pv) do { \
        const float* fp_ = fij + (size_t)(pv) * NB; \
        if (kgrp < 3) { \
            T.f0 = *(const float4*)(fp_ + (kgrp << 3)); \
            T.f1 = *(const float4*)(fp_ + (kgrp << 3) + 4); \
        } else { \
            T.f0 = make_float4(fp_[24], 0.f, 0.f, 0.f); \
            T.f1 = make_float4(0.f, 0.f, 0.f, 0.f); \
        } \
        T.se_own = src[pv]; \
        T.de_own = dst[pv]; \
        T.rij_own = rij[pv]; \
    } while (0)

    TileReg cur, nxt;
    int pvB;
    {
        int pvA = perm[((size_t)gw << 4) + lrow];
        GATHER(cur, pvA);
        int i2 = gw + NW; i2 = (i2 < NT) ? i2 : (NT - 1);
        pvB = perm[((size_t)i2 << 4) + lrow];
    }

    for (int tb = gw; tb < NT; tb += NW) {
        // ---- (1) epilogue prep for CUR: shfls + xv loads FIRST (vmem head) ----
        float Cf_own = (cur.rij_own < CUTOFF_F)
                     ? 0.5f * (__cosf(cur.rij_own * PI_OVER_CUTOFF) + 1.0f) : 0.0f;
        int se4[4], de4[4]; float Cf[4];
        #pragma unroll
        for (int r = 0; r < 4; ++r) {
            se4[r] = __shfl(cur.se_own, (kgrp << 2) + r);
            Cf[r]  = __shfl(Cf_own, (kgrp << 2) + r);
            de4[r] = __shfl(cur.de_own, (kgrp << 2) + r);
        }
        bf16x8 xv4[4];
        #pragma unroll
        for (int r = 0; r < 4; ++r)
            xv4[r] = *(const bf16x8*)&xb[(size_t)se4[r] * FDIM + (lrow << 3)];

        // ---- (2) next-tile gathers AFTER xv (these pad xv's vmcnt slack) ----
        GATHER(nxt, pvB);
        int i3 = tb + 2 * NW; i3 = (i3 < NT) ? i3 : (NT - 1);
        pvB = perm[((size_t)i3 << 4) + lrow];

        // ---- (3) GEMM1: H = swish(fij_pad @ W1 + b1) -> hw (wave-local) ----
        bf16x8 a;
        a[0] = (__bf16)cur.f0.x; a[1] = (__bf16)cur.f0.y;
        a[2] = (__bf16)cur.f0.z; a[3] = (__bf16)cur.f0.w;
        a[4] = (__bf16)cur.f1.x; a[5] = (__bf16)cur.f1.y;
        a[6] = (__bf16)cur.f1.z; a[7] = (__bf16)cur.f1.w;

        #pragma unroll
        for (int n = 0; n < 8; ++n) {
            f32x4 h = __builtin_amdgcn_mfma_f32_16x16x32_bf16(a, w1f[n], zero, 0, 0, 0);
            #pragma unroll
            for (int r = 0; r < 4; ++r) {
                int hrow = (kgrp << 2) + r;
                float hv = swish_f(h[r] + b1r[n]);
                int byte = (hrow << 8) + (((n << 4) + lrow) << 1);
                byte ^= SWZ(hrow);
                *(__bf16*)((char*)hw + byte) = (__bf16)hv;
            }
        }
        // no barrier: hw is wave-local (same-wave DS ops are ordered)

        // ---- (4) GEMM2: Wfilt = H @ W2 (B-frags batched from LDS) ----
        f32x4 acc[8];
        #pragma unroll
        for (int n = 0; n < 8; ++n) acc[n] = zero;

        #pragma unroll
        for (int ks = 0; ks < 4; ++ks) {
            int byte = (lrow << 8) + (ks << 6) + (kgrp << 4);
            byte ^= SWZ(lrow);
            bf16x8 a2 = *(const bf16x8*)((const char*)hw + byte);
            bf16x8 bfr[8];
            #pragma unroll
            for (int n = 0; n < 8; ++n)
                bfr[n] = *(const bf16x8*)((const char*)w2s + (((ks << 3) + n) << 10) + (l << 4));
            #pragma unroll
            for (int n = 0; n < 8; ++n)
                acc[n] = __builtin_amdgcn_mfma_f32_16x16x32_bf16(a2, bfr[n], acc[n], 0, 0, 0);
        }

        // ---- (5) Epilogue: uni fast path + run-compressed atomics ----
        int d0 = __shfl(cur.de_own, 0);
        bool uni = __all(cur.de_own == d0);

        if (uni) {
            const size_t dbase = (size_t)d0 * FDIM;
            #pragma unroll
            for (int n = 0; n < 8; ++n) {
                float s = 0.f;
                #pragma unroll
                for (int r = 0; r < 4; ++r)
                    s += (float)xv4[r][n] * (acc[n][r] + b2r[n]) * Cf[r];
                s += __shfl_xor(s, 16);
                s += __shfl_xor(s, 32);
                if (kgrp == 0) unsafeAtomicAdd(&agg[dbase + (n << 4) + lrow], s);
            }
        } else {
            const bool brk0 = (de4[0] != de4[1]);
            const bool brk1 = (de4[1] != de4[2]);
            const bool brk2 = (de4[2] != de4[3]);
            #pragma unroll
            for (int n = 0; n < 8; ++n) {
                int col = (n << 4) + lrow;
                float m[4];
                #pragma unroll
                for (int r = 0; r < 4; ++r)
                    m[r] = (float)xv4[r][n] * (acc[n][r] + b2r[n]) * Cf[r];
                float run = m[0];
                if (brk0) { unsafeAtomicAdd(&agg[(size_t)de4[0] * FDIM + col], run); run = 0.f; }
                run += m[1];
                if (brk1) { unsafeAtomicAdd(&agg[(size_t)de4[1] * FDIM + col], run); run = 0.f; }
                run += m[2];
                if (brk2) { unsafeAtomicAdd(&agg[(size_t)de4[2] * FDIM + col], run); run = 0.f; }
                run += m[3];
                unsafeAtomicAdd(&agg[(size_t)de4[3] * FDIM + col], run);
            }
        }

        cur = nxt;
    }
    #undef GATHER
}

extern "C" void kernel_launch(void* const* d_in, const int* in_sizes, int n_in,
                              void* d_out, int out_size, void* d_ws, size_t ws_size,
                              hipStream_t stream)
{
    const float* feat   = (const float*)d_in[0];
    const float* fij    = (const float*)d_in[1];
    const float* rij    = (const float*)d_in[2];
    const int*   src    = (const int*)d_in[3];
    const int*   dst    = (const int*)d_in[4];
    const float* W_in2f = (const float*)d_in[5];
    const float* W_f1   = (const float*)d_in[6];
    const float* b_f1   = (const float*)d_in[7];
    const float* W_f2   = (const float*)d_in[8];
    const float* b_f2   = (const float*)d_in[9];
    const float* W_out  = (const float*)d_in[10];
    const float* b_out  = (const float*)d_in[11];
    float* out = (float*)d_out;

    // ws layout, total 33,333,696 B (< r15-proven 147.7 MB watermark)
    char* ws = (char*)d_ws;
    __bf16* xb    = (__bf16*)ws;                  // 12,800,000 B
    __bf16* w1p   = (__bf16*)(ws + 12800000);     //      8,192 B
    __bf16* w2p   = (__bf16*)(ws + 12808192);     //     32,768 B
    __bf16* winp  = (__bf16*)(ws + 12840960);     //     32,768 B
    __bf16* woutp = (__bf16*)(ws + 12873728);     //     32,768 B
    int*    bt    = (int*)(ws + 12906496);        //      1,024 B (197 ints)
    int*    gh    = (int*)(ws + 12907520);        //    613,088 B
    int*    off   = (int*)(ws + 13520608);        //    613,088 B
    int*    ebkt  = (int*)(ws + 14133696);        //  6,400,000 B
    int*    ebuf1 = (int*)(ws + 20533696);        //  6,400,000 B
    int*    perm  = (int*)(ws + 26933696);        //  6,400,000 B
    float*  agg   = out;                          // accumulate into d_out

    hipMemsetAsync(agg, 0, (size_t)N_ATOMS * FDIM * sizeof(float), stream);

    // LDS-radix group-by-dst (no global atomics)
    radix1_hist_kernel<<<P1B, 256, 0, stream>>>(dst, ebkt, gh);
    scan_buckets_kernel<<<RB, 256, 0, stream>>>(gh, off, bt);
    scan_base_kernel<<<1, 256, 0, stream>>>(bt);
    radix1_place_kernel<<<P1B, 256, 0, stream>>>(ebkt, off, bt, ebuf1);
    radix2_kernel<<<RB, 1024, 0, stream>>>(ebuf1, dst, bt, perm);

    pack_b_kernel<<<(4096 + 255) / 256, 256, 0, stream>>>(W_f1, w1p, NB, 1);
    pack_b_kernel<<<(16384 + 255) / 256, 256, 0, stream>>>(W_f2, w2p, 128, 4);
    pack_b_kernel<<<(16384 + 255) / 256, 256, 0, stream>>>(W_in2f, winp, 128, 4);
    pack_b_kernel<<<(16384 + 255) / 256, 256, 0, stream>>>(W_out, woutp, 128, 4);

    // x = feat @ W_in2f  -> xb (bf16, permuted)
    node_mfma_kernel<<<(N_ATOMS / 16 + 7) / 8, 512, 0, stream>>>(
        feat, winp, nullptr, xb, nullptr, 0);

    edge_kernel<<<NBLK, 512, 0, stream>>>(
        fij, rij, src, dst, perm, w1p, b_f1, w2p, b_f2, xb, agg);

    // out = swish(agg @ W_out + b_out)  (in-place per 16-row tile)
    node_mfma_kernel<<<(N_ATOMS / 16 + 7) / 8, 512, 0, stream>>>(
        agg, woutp, b_out, nullptr, out, 1);
}